// Round 5
// baseline (973.068 us; speedup 1.0000x reference)
//
#include <hip/hip_runtime.h>
#include <hip/hip_bf16.h>
#include <math.h>

constexpr int BATCH = 256;
constexpr int SEQ   = 128;
constexpr int FEAT  = 512;
constexpr int HID   = 512;
constexpr int G3    = 1536;

typedef __bf16 bf16x8 __attribute__((ext_vector_type(8)));
typedef float  f32x4  __attribute__((ext_vector_type(4)));

// ---------------------------------------------------------------------------
// fp32 -> bf16 convert (vectorized, 8/thread)
// ---------------------------------------------------------------------------
__global__ __launch_bounds__(256) void convert_bf16(
    const float* __restrict__ in, __hip_bfloat16* __restrict__ out, int n)
{
  int i = (blockIdx.x * 256 + threadIdx.x) * 8;
  if (i >= n) return;
  float4 v0 = *(const float4*)&in[i];
  float4 v1 = *(const float4*)&in[i + 4];
  __hip_bfloat16 o[8];
  o[0] = (__hip_bfloat16)v0.x; o[1] = (__hip_bfloat16)v0.y;
  o[2] = (__hip_bfloat16)v0.z; o[3] = (__hip_bfloat16)v0.w;
  o[4] = (__hip_bfloat16)v1.x; o[5] = (__hip_bfloat16)v1.y;
  o[6] = (__hip_bfloat16)v1.z; o[7] = (__hip_bfloat16)v1.w;
  *(int4*)&out[i] = *(int4*)o;
}

// ---------------------------------------------------------------------------
// transpose + convert: in[512][1536] f32 -> outT[1536][512] bf16
// ---------------------------------------------------------------------------
__global__ __launch_bounds__(256) void transpose_convert(
    const float* __restrict__ in, __hip_bfloat16* __restrict__ outT)
{
  __shared__ float tile[32][33];
  const int c0 = blockIdx.x * 32;
  const int r0 = blockIdx.y * 32;
  const int tid = threadIdx.x;
  {
    int row = tid >> 3, c4 = tid & 7;
    float4 v = *(const float4*)&in[(size_t)(r0 + row) * G3 + c0 + c4 * 4];
    tile[row][c4 * 4 + 0] = v.x;
    tile[row][c4 * 4 + 1] = v.y;
    tile[row][c4 * 4 + 2] = v.z;
    tile[row][c4 * 4 + 3] = v.w;
  }
  __syncthreads();
  {
    int rowT = tid >> 3, c4 = tid & 7;
    __hip_bfloat16 o[4];
#pragma unroll
    for (int e = 0; e < 4; ++e)
      o[e] = (__hip_bfloat16)tile[c4 * 4 + e][rowT];
    *(int2*)&outT[(size_t)(c0 + rowT) * FEAT + r0 + c4 * 4] = *(int2*)o;
  }
}

// ---------------------------------------------------------------------------
// proj (same as R4: global_load_lds + XOR swizzle, 0 bank conflicts)
// ---------------------------------------------------------------------------
__global__ __launch_bounds__(256) void proj_mfma(
    const __hip_bfloat16* __restrict__ xb, const __hip_bfloat16* __restrict__ WkT,
    const float* __restrict__ bias, __hip_bfloat16* __restrict__ xp)
{
  __shared__ __align__(16) __hip_bfloat16 As[128 * 64];
  __shared__ __align__(16) __hip_bfloat16 Bs[128 * 64];

  const int tid = threadIdx.x;
  const int wave = tid >> 6, l = tid & 63;
  const int wm = wave >> 1, wn = wave & 1;
  const int m0 = blockIdx.y * 128;
  const int n0 = blockIdx.x * 128;
  const int lr = l & 15, lh = l >> 4;
  const int swz = lr & 7;

  const int srow = l >> 3;
  const int schk = l & 7;
  const int wrow = wave * 32;

  f32x4 acc[4][4] = {};

  for (int k0 = 0; k0 < FEAT; k0 += 64) {
    __syncthreads();
#pragma unroll
    for (int i = 0; i < 4; ++i) {
      int r = wrow + i * 8 + srow;
      const __hip_bfloat16* srcA = &xb[(size_t)(m0 + r) * FEAT + k0 + ((schk ^ srow) * 8)];
      __builtin_amdgcn_global_load_lds(
          (const __attribute__((address_space(1))) void*)srcA,
          (__attribute__((address_space(3))) void*)&As[(wrow + i * 8) * 64], 16, 0, 0);
    }
#pragma unroll
    for (int i = 0; i < 4; ++i) {
      int r = wrow + i * 8 + srow;
      const __hip_bfloat16* srcB = &WkT[(size_t)(n0 + r) * FEAT + k0 + ((schk ^ srow) * 8)];
      __builtin_amdgcn_global_load_lds(
          (const __attribute__((address_space(1))) void*)srcB,
          (__attribute__((address_space(3))) void*)&Bs[(wrow + i * 8) * 64], 16, 0, 0);
    }
    __syncthreads();

#pragma unroll
    for (int ks = 0; ks < 2; ++ks) {
      bf16x8 a[4], b[4];
#pragma unroll
      for (int i = 0; i < 4; ++i) {
        int row = wm * 64 + i * 16 + lr;
        a[i] = *(const bf16x8*)&As[row * 64 + (((ks * 4 + lh) ^ swz) * 8)];
      }
#pragma unroll
      for (int j = 0; j < 4; ++j) {
        int row = wn * 64 + j * 16 + lr;
        b[j] = *(const bf16x8*)&Bs[row * 64 + (((ks * 4 + lh) ^ swz) * 8)];
      }
#pragma unroll
      for (int i = 0; i < 4; ++i)
#pragma unroll
        for (int j = 0; j < 4; ++j)
          acc[i][j] = __builtin_amdgcn_mfma_f32_16x16x32_bf16(a[i], b[j], acc[i][j], 0, 0, 0);
    }
  }

  float bv[4];
#pragma unroll
  for (int j = 0; j < 4; ++j)
    bv[j] = bias[n0 + wn * 64 + j * 16 + lr];
#pragma unroll
  for (int i = 0; i < 4; ++i)
#pragma unroll
    for (int j = 0; j < 4; ++j) {
      int n = n0 + wn * 64 + j * 16 + lr;
#pragma unroll
      for (int r = 0; r < 4; ++r) {
        int m = m0 + wm * 64 + i * 16 + lh * 4 + r;
        xp[(size_t)m * G3 + n] = (__hip_bfloat16)(acc[i][j][r] + bv[j]);
      }
    }
}

// ---------------------------------------------------------------------------
// Persistent GRU recurrence, relaxed-atomic sync (NO acq/rel -> no L2
// writeback/invalidate storms). Grid = 256: blockIdx.x = jt*16 + bt.
//   bt: batch rows bt*16..+16 (sync group); jt: j-cols jt*32..+32.
// W slice (96x512 bf16) in LDS for all 128 steps. h state fp32 in regs.
// h exchange: relaxed agent-scope atomic u64 loads / u32 stores (sc0+sc1
// -> read/write at coherence point, no stale L1/L2, no cache-maint ops).
// Barrier: monotonic arrive counter + gen broadcast, relaxed only;
// ordering from __syncthreads()' implicit vmcnt(0) drain.
// ---------------------------------------------------------------------------
__global__ __launch_bounds__(256, 1) void gru_persist(
    __hip_bfloat16* __restrict__ hbA, __hip_bfloat16* __restrict__ hbB,
    float* __restrict__ h32,
    const __hip_bfloat16* __restrict__ xp,   // [(b*SEQ+t)][1536] bf16
    const __hip_bfloat16* __restrict__ WrT,  // [1536][512] bf16
    const float* __restrict__ br,
    int* arrive, int* gen)
{
  extern __shared__ char smem[];
  __hip_bfloat16* W_s = (__hip_bfloat16*)smem;              // [96][520]  99,840 B
  __hip_bfloat16* h_s = (__hip_bfloat16*)(smem + 99840);    // [16][520]  16,640 B
  float*          red = (float*)(smem + 116480);            // [2][16][100] 12,800 B

  const int tid = threadIdx.x;
  const int bt = blockIdx.x & 15;
  const int jt = blockIdx.x >> 4;
  const int wave = tid >> 6, l = tid & 63;
  const int kh = wave & 1, ch = wave >> 1;
  const int lr = l & 15, lk = (l >> 4) * 8, lh = l >> 4;

  // ---- one-time: stage Wr slice (96 rows x 512 k), plain loads ----
#pragma unroll
  for (int i = 0; i < 24; ++i) {
    int q = tid + i * 256;
    int row = q >> 6;
    int c = q & 63;
    int g = row >> 5, jl = row & 31;
    int n = g * HID + jt * 32 + jl;
    *(int4*)&W_s[row * 520 + c * 8] = *(const int4*)&WrT[(size_t)n * HID + c * 8];
  }

  // ---- per-thread epilogue ownership: (m, q4) -> j pair {q4*2, q4*2+1}
  const int m = tid >> 4, q4 = tid & 15;
  const int b = bt * 16 + m;
  const int jl0 = q4 * 2;             // local j of first element
  const int jg0 = jt * 32 + jl0;      // global j of first element
  float brz[2], brr[2], brh[2], hreg[2];
#pragma unroll
  for (int p = 0; p < 2; ++p) {
    brz[p] = br[jg0 + p];
    brr[p] = br[HID + jg0 + p];
    brh[p] = br[2 * HID + jg0 + p];
    hreg[p] = 0.f;
  }

  // preload xp for t=0 (u32 = 2 consecutive bf16)
  float xzv[2], xrv[2], xhv[2];
  {
    const __hip_bfloat16* xb_ = &xp[((size_t)b * SEQ + 0) * G3 + jg0];
    unsigned int uz = *(const unsigned int*)&xb_[0];
    unsigned int ur = *(const unsigned int*)&xb_[HID];
    unsigned int uh = *(const unsigned int*)&xb_[2 * HID];
    xzv[0] = (float)((__hip_bfloat16*)&uz)[0]; xzv[1] = (float)((__hip_bfloat16*)&uz)[1];
    xrv[0] = (float)((__hip_bfloat16*)&ur)[0]; xrv[1] = (float)((__hip_bfloat16*)&ur)[1];
    xhv[0] = (float)((__hip_bfloat16*)&uh)[0]; xhv[1] = (float)((__hip_bfloat16*)&uh)[1];
  }
  __syncthreads();   // W_s ready

  for (int t = 0; t < SEQ; ++t) {
    const __hip_bfloat16* cur = (t & 1) ? hbB : hbA;
    __hip_bfloat16* nxt = (t & 1) ? hbA : hbB;

    // ---- stage h rows via relaxed agent atomic u64 loads (coherent) ----
    {
      const unsigned long long* cu = (const unsigned long long*)cur;
#pragma unroll
      for (int i = 0; i < 8; ++i) {
        int q = tid + i * 256;        // 0..2047
        int r = q >> 7, c = q & 127;  // row, u64-chunk (4 bf16)
        unsigned long long v = __hip_atomic_load(
            &cu[(size_t)(bt * 16 + r) * 128 + c],
            __ATOMIC_RELAXED, __HIP_MEMORY_SCOPE_AGENT);
        *(unsigned long long*)&h_s[r * 520 + c * 4] = v;
      }
    }
    __syncthreads();

    // ---- MFMA: M=16, N=48 (col-half ch), K=256 (K-half kh) ----
    f32x4 acc[3] = {};
#pragma unroll
    for (int ks = 0; ks < 8; ++ks) {
      int k = kh * 256 + ks * 32 + lk;
      bf16x8 a = *(const bf16x8*)&h_s[lr * 520 + k];
#pragma unroll
      for (int f = 0; f < 3; ++f) {
        bf16x8 bfrag = *(const bf16x8*)&W_s[(ch * 48 + f * 16 + lr) * 520 + k];
        acc[f] = __builtin_amdgcn_mfma_f32_16x16x32_bf16(a, bfrag, acc[f], 0, 0, 0);
      }
    }
#pragma unroll
    for (int f = 0; f < 3; ++f)
#pragma unroll
      for (int i = 0; i < 4; ++i)
        red[kh * 1600 + (lh * 4 + i) * 100 + ch * 48 + f * 16 + lr] = acc[f][i];
    __syncthreads();

    // ---- epilogue: 2 consecutive j per thread; pack u32 atomic store ----
    {
      float hn[2];
#pragma unroll
      for (int p = 0; p < 2; ++p) {
        int jl = jl0 + p;
        float rz = red[m * 100 + jl]      + red[1600 + m * 100 + jl];
        float rr = red[m * 100 + 32 + jl] + red[1600 + m * 100 + 32 + jl];
        float rh = red[m * 100 + 64 + jl] + red[1600 + m * 100 + 64 + jl];
        rz += brz[p]; rr += brr[p]; rh += brh[p];
        float z  = 1.f / (1.f + __expf(-(xzv[p] + rz)));
        float rg = 1.f / (1.f + __expf(-(xrv[p] + rr)));
        float hh = fmaxf(xhv[p] + rg * rh, 0.f);
        hn[p] = z * hreg[p] + (1.f - z) * hh;
        hreg[p] = hn[p];
      }
      if (t < SEQ - 1) {
        __hip_bfloat16 h0 = (__hip_bfloat16)hn[0], h1 = (__hip_bfloat16)hn[1];
        unsigned int pk = (unsigned int)*(unsigned short*)&h0 |
                          ((unsigned int)*(unsigned short*)&h1 << 16);
        __hip_atomic_store(
            (unsigned int*)&nxt[(size_t)b * HID + jg0], pk,
            __ATOMIC_RELAXED, __HIP_MEMORY_SCOPE_AGENT);

        // prefetch xp for t+1 (overlaps the barrier below)
        const __hip_bfloat16* xb_ = &xp[((size_t)b * SEQ + t + 1) * G3 + jg0];
        unsigned int uz = *(const unsigned int*)&xb_[0];
        unsigned int ur = *(const unsigned int*)&xb_[HID];
        unsigned int uh = *(const unsigned int*)&xb_[2 * HID];
        xzv[0] = (float)((__hip_bfloat16*)&uz)[0]; xzv[1] = (float)((__hip_bfloat16*)&uz)[1];
        xrv[0] = (float)((__hip_bfloat16*)&ur)[0]; xrv[1] = (float)((__hip_bfloat16*)&ur)[1];
        xhv[0] = (float)((__hip_bfloat16*)&uh)[0]; xhv[1] = (float)((__hip_bfloat16*)&uh)[1];
      }
    }

    // ---- group barrier: monotonic arrive + gen broadcast, relaxed ----
    if (t < SEQ - 1) {
      __syncthreads();   // drains every wave's vmcnt -> h stores complete
      if (tid == 0) {
        int a = __hip_atomic_fetch_add(&arrive[bt], 1, __ATOMIC_RELAXED,
                                       __HIP_MEMORY_SCOPE_AGENT);
        if (a == 16 * t + 15) {
          __hip_atomic_store(&gen[bt], t + 1, __ATOMIC_RELAXED,
                             __HIP_MEMORY_SCOPE_AGENT);
        } else {
          while (__hip_atomic_load(&gen[bt], __ATOMIC_RELAXED,
                                   __HIP_MEMORY_SCOPE_AGENT) < t + 1)
            __builtin_amdgcn_s_sleep(2);
        }
      }
      __syncthreads();
    }
  }

  // final fp32 h (own tile only; kernel-end flush publishes for head)
#pragma unroll
  for (int p = 0; p < 2; ++p)
    h32[(size_t)b * HID + jg0 + p] = hreg[p];
}

// ---------------------------------------------------------------------------
// head: out[b] = h32[b][:] . Wd + bd
// ---------------------------------------------------------------------------
__global__ __launch_bounds__(64) void head_kernel(
    const float* __restrict__ h32, const float* __restrict__ Wd,
    const float* __restrict__ bd, float* __restrict__ out)
{
  int b = blockIdx.x, l = threadIdx.x;
  const float* hr = &h32[(size_t)b * HID];
  float s = 0.f;
#pragma unroll
  for (int i = 0; i < 8; ++i)
    s += hr[l + i * 64] * Wd[l + i * 64];
#pragma unroll
  for (int off = 32; off; off >>= 1) s += __shfl_down(s, off);
  if (l == 0) out[b] = s + bd[0];
}

// ---------------------------------------------------------------------------
extern "C" void kernel_launch(void* const* d_in, const int* in_sizes, int n_in,
                              void* d_out, int out_size, void* d_ws, size_t ws_size,
                              hipStream_t stream) {
  const float* x    = (const float*)d_in[0];
  const float* Wk   = (const float*)d_in[1];
  const float* Wr   = (const float*)d_in[2];
  const float* bias = (const float*)d_in[3];
  const float* Wd   = (const float*)d_in[4];
  const float* bd   = (const float*)d_in[5];
  float* out = (float*)d_out;

  char* ws = (char*)d_ws;
  size_t off = 0;
  __hip_bfloat16* xp  = (__hip_bfloat16*)(ws + off); off += (size_t)BATCH * SEQ * G3 * 2;
  __hip_bfloat16* xb  = (__hip_bfloat16*)(ws + off); off += (size_t)BATCH * SEQ * FEAT * 2;
  __hip_bfloat16* WkT = (__hip_bfloat16*)(ws + off); off += (size_t)G3 * FEAT * 2;
  __hip_bfloat16* WrT = (__hip_bfloat16*)(ws + off); off += (size_t)G3 * HID * 2;
  float*          h32 = (float*)(ws + off);          off += (size_t)BATCH * HID * 4;
  __hip_bfloat16* hb0 = (__hip_bfloat16*)(ws + off); off += (size_t)BATCH * HID * 2;
  __hip_bfloat16* hb1 = (__hip_bfloat16*)(ws + off); off += (size_t)BATCH * HID * 2;
  int*            arrive = (int*)(ws + off);         off += 16 * sizeof(int);
  int*            gen    = (int*)(ws + off);         off += 16 * sizeof(int);

  convert_bf16<<<(BATCH * SEQ * FEAT) / (256 * 8), 256, 0, stream>>>(x, xb, BATCH * SEQ * FEAT);
  transpose_convert<<<dim3(G3 / 32, FEAT / 32), 256, 0, stream>>>(Wk, WkT);
  transpose_convert<<<dim3(G3 / 32, HID  / 32), 256, 0, stream>>>(Wr, WrT);

  proj_mfma<<<dim3(G3 / 128, (BATCH * SEQ) / 128), 256, 0, stream>>>(xb, WkT, bias, xp);

  // zero: h t=0 buffer, barrier state (arrive+gen contiguous, 128 B)
  hipMemsetAsync(hb0, 0, (size_t)BATCH * HID * sizeof(__hip_bfloat16), stream);
  hipMemsetAsync(arrive, 0, 32 * sizeof(int), stream);

  const float* br = bias + G3;
  const size_t lds_bytes = 129280;
  hipFuncSetAttribute((const void*)gru_persist,
                      hipFuncAttributeMaxDynamicSharedMemorySize, (int)lds_bytes);
  {
    void* args[] = {(void*)&hb0, (void*)&hb1, (void*)&h32, (void*)&xp,
                    (void*)&WrT, (void*)&br, (void*)&arrive, (void*)&gen};
    hipLaunchCooperativeKernel((void*)gru_persist, dim3(256), dim3(256),
                               args, (unsigned)lds_bytes, stream);
  }

  head_kernel<<<256, 64, 0, stream>>>(h32, Wd, bd, out);
}

// Round 6
// 551.799 us; speedup vs baseline: 1.7634x; 1.7634x over previous
//
#include <hip/hip_runtime.h>
#include <hip/hip_bf16.h>
#include <math.h>

constexpr int BATCH = 256;
constexpr int SEQ   = 128;
constexpr int FEAT  = 512;
constexpr int HID   = 512;
constexpr int G3    = 1536;

typedef __bf16 bf16x8 __attribute__((ext_vector_type(8)));
typedef float  f32x4  __attribute__((ext_vector_type(4)));

// ---------------------------------------------------------------------------
// fp32 -> bf16 convert (vectorized, 8/thread)
// ---------------------------------------------------------------------------
__global__ __launch_bounds__(256) void convert_bf16(
    const float* __restrict__ in, __hip_bfloat16* __restrict__ out, int n)
{
  int i = (blockIdx.x * 256 + threadIdx.x) * 8;
  if (i >= n) return;
  float4 v0 = *(const float4*)&in[i];
  float4 v1 = *(const float4*)&in[i + 4];
  __hip_bfloat16 o[8];
  o[0] = (__hip_bfloat16)v0.x; o[1] = (__hip_bfloat16)v0.y;
  o[2] = (__hip_bfloat16)v0.z; o[3] = (__hip_bfloat16)v0.w;
  o[4] = (__hip_bfloat16)v1.x; o[5] = (__hip_bfloat16)v1.y;
  o[6] = (__hip_bfloat16)v1.z; o[7] = (__hip_bfloat16)v1.w;
  *(int4*)&out[i] = *(int4*)o;
}

// ---------------------------------------------------------------------------
// transpose + convert: in[512][1536] f32 -> outT[1536][512] bf16
// ---------------------------------------------------------------------------
__global__ __launch_bounds__(256) void transpose_convert(
    const float* __restrict__ in, __hip_bfloat16* __restrict__ outT)
{
  __shared__ float tile[32][33];
  const int c0 = blockIdx.x * 32;
  const int r0 = blockIdx.y * 32;
  const int tid = threadIdx.x;
  {
    int row = tid >> 3, c4 = tid & 7;
    float4 v = *(const float4*)&in[(size_t)(r0 + row) * G3 + c0 + c4 * 4];
    tile[row][c4 * 4 + 0] = v.x;
    tile[row][c4 * 4 + 1] = v.y;
    tile[row][c4 * 4 + 2] = v.z;
    tile[row][c4 * 4 + 3] = v.w;
  }
  __syncthreads();
  {
    int rowT = tid >> 3, c4 = tid & 7;
    __hip_bfloat16 o[4];
#pragma unroll
    for (int e = 0; e < 4; ++e)
      o[e] = (__hip_bfloat16)tile[c4 * 4 + e][rowT];
    *(int2*)&outT[(size_t)(c0 + rowT) * FEAT + r0 + c4 * 4] = *(int2*)o;
  }
}

// ---------------------------------------------------------------------------
// proj: 128x128 tile, BK=64, 2-phase double-buffered global_load_lds with
// XOR source/read swizzle (0 bank conflicts, one barrier per K-tile).
// ---------------------------------------------------------------------------
__global__ __launch_bounds__(256) void proj_mfma(
    const __hip_bfloat16* __restrict__ xb, const __hip_bfloat16* __restrict__ WkT,
    const float* __restrict__ bias, __hip_bfloat16* __restrict__ xp)
{
  __shared__ __align__(16) __hip_bfloat16 As[2][128 * 64];  // 2 x 16 KB
  __shared__ __align__(16) __hip_bfloat16 Bs[2][128 * 64];

  const int tid = threadIdx.x;
  const int wave = tid >> 6, l = tid & 63;
  const int wm = wave >> 1, wn = wave & 1;
  const int m0 = blockIdx.y * 128;
  const int n0 = blockIdx.x * 128;
  const int lr = l & 15, lh = l >> 4;
  const int swz = lr & 7;

  const int srow = l >> 3;
  const int schk = l & 7;
  const int wrow = wave * 32;

  f32x4 acc[4][4] = {};

#define PROJ_STAGE(K0, SEL)                                                      \
  {                                                                              \
    _Pragma("unroll")                                                            \
    for (int i = 0; i < 4; ++i) {                                                \
      int r = wrow + i * 8 + srow;                                               \
      const __hip_bfloat16* srcA =                                               \
          &xb[(size_t)(m0 + r) * FEAT + (K0) + ((schk ^ srow) * 8)];             \
      __builtin_amdgcn_global_load_lds(                                          \
          (const __attribute__((address_space(1))) void*)srcA,                   \
          (__attribute__((address_space(3))) void*)&As[SEL][(wrow + i * 8) * 64],\
          16, 0, 0);                                                             \
    }                                                                            \
    _Pragma("unroll")                                                            \
    for (int i = 0; i < 4; ++i) {                                                \
      int r = wrow + i * 8 + srow;                                               \
      const __hip_bfloat16* srcB =                                               \
          &WkT[(size_t)(n0 + r) * FEAT + (K0) + ((schk ^ srow) * 8)];            \
      __builtin_amdgcn_global_load_lds(                                          \
          (const __attribute__((address_space(1))) void*)srcB,                   \
          (__attribute__((address_space(3))) void*)&Bs[SEL][(wrow + i * 8) * 64],\
          16, 0, 0);                                                             \
    }                                                                            \
  }

  PROJ_STAGE(0, 0);
  __syncthreads();

  int cur = 0;
  for (int kt = 0; kt < 8; ++kt) {
    if (kt < 7) PROJ_STAGE((kt + 1) * 64, cur ^ 1);

#pragma unroll
    for (int ks = 0; ks < 2; ++ks) {
      bf16x8 a[4], b[4];
#pragma unroll
      for (int i = 0; i < 4; ++i) {
        int row = wm * 64 + i * 16 + lr;
        a[i] = *(const bf16x8*)&As[cur][row * 64 + (((ks * 4 + lh) ^ swz) * 8)];
      }
#pragma unroll
      for (int j = 0; j < 4; ++j) {
        int row = wn * 64 + j * 16 + lr;
        b[j] = *(const bf16x8*)&Bs[cur][row * 64 + (((ks * 4 + lh) ^ swz) * 8)];
      }
#pragma unroll
      for (int i = 0; i < 4; ++i)
#pragma unroll
        for (int j = 0; j < 4; ++j)
          acc[i][j] = __builtin_amdgcn_mfma_f32_16x16x32_bf16(a[i], b[j], acc[i][j], 0, 0, 0);
    }
    __syncthreads();   // drains vmcnt -> next buffer staged; guards reuse
    cur ^= 1;
  }

  float bv[4];
#pragma unroll
  for (int j = 0; j < 4; ++j)
    bv[j] = bias[n0 + wn * 64 + j * 16 + lr];
#pragma unroll
  for (int i = 0; i < 4; ++i)
#pragma unroll
    for (int j = 0; j < 4; ++j) {
      int n = n0 + wn * 64 + j * 16 + lr;
#pragma unroll
      for (int r = 0; r < 4; ++r) {
        int m = m0 + wm * 64 + i * 16 + lh * 4 + r;
        xp[(size_t)m * G3 + n] = (__hip_bfloat16)(acc[i][j][r] + bv[j]);
      }
    }
#undef PROJ_STAGE
}

// ---------------------------------------------------------------------------
// Persistent GRU recurrence, v3.
//   - W register-stationary: 24 bf16x8 fragments per lane, loaded once.
//   - h fragments: direct global->reg relaxed agent u64 atomic loads.
//   - Barrier: single-writer flag per block (slots[bt][jt], 128-B line per
//     group), monotonic, relaxed-only. No RMW anywhere.
// Grid 256: blockIdx.x = jt*16 + bt. LDS = 12.8 KB reduction buffer only.
// ---------------------------------------------------------------------------
__global__ __launch_bounds__(256, 1) void gru_persist(
    __hip_bfloat16* __restrict__ hbA, __hip_bfloat16* __restrict__ hbB,
    float* __restrict__ h32,
    const __hip_bfloat16* __restrict__ xp,   // [(b*SEQ+t)][1536] bf16
    const __hip_bfloat16* __restrict__ WrT,  // [1536][512] bf16
    const float* __restrict__ br,
    int* slots)                               // [16][32] ints (128 B per group)
{
  __shared__ float red[2 * 16 * 100];         // [kh][m][col], 12.8 KB

  const int tid = threadIdx.x;
  const int bt = blockIdx.x & 15;
  const int jt = blockIdx.x >> 4;
  const int wave = tid >> 6, l = tid & 63;
  const int kh = wave & 1, ch = wave >> 1;
  const int lr = l & 15, lh = l >> 4;

  // ---- one-time: W fragments -> registers (24 x 16B per lane) ----
  bf16x8 wfrag[8][3];
#pragma unroll
  for (int f = 0; f < 3; ++f) {
    int r = ch * 48 + f * 16 + lr;                    // red/W row id 0..95
    int n = (r >> 5) * HID + jt * 32 + (r & 31);      // global gate-col
    const __hip_bfloat16* wp = &WrT[(size_t)n * HID + kh * 256 + lh * 8];
#pragma unroll
    for (int ks = 0; ks < 8; ++ks)
      wfrag[ks][f] = *(const bf16x8*)&wp[ks * 32];
  }

  // ---- per-thread epilogue ownership: (m, q4) -> j pair {q4*2, q4*2+1}
  const int m = tid >> 4, q4 = tid & 15;
  const int b = bt * 16 + m;
  const int jl0 = q4 * 2;
  const int jg0 = jt * 32 + jl0;
  float brz[2], brr[2], brh[2], hreg[2];
#pragma unroll
  for (int p = 0; p < 2; ++p) {
    brz[p] = br[jg0 + p];
    brr[p] = br[HID + jg0 + p];
    brh[p] = br[2 * HID + jg0 + p];
    hreg[p] = 0.f;
  }

  // preload xp for t=0
  float xzv[2], xrv[2], xhv[2];
  {
    const __hip_bfloat16* xb_ = &xp[((size_t)b * SEQ + 0) * G3 + jg0];
    unsigned int uz = *(const unsigned int*)&xb_[0];
    unsigned int ur = *(const unsigned int*)&xb_[HID];
    unsigned int uh = *(const unsigned int*)&xb_[2 * HID];
    xzv[0] = (float)((__hip_bfloat16*)&uz)[0]; xzv[1] = (float)((__hip_bfloat16*)&uz)[1];
    xrv[0] = (float)((__hip_bfloat16*)&ur)[0]; xrv[1] = (float)((__hip_bfloat16*)&ur)[1];
    xhv[0] = (float)((__hip_bfloat16*)&uh)[0]; xhv[1] = (float)((__hip_bfloat16*)&uh)[1];
  }

  const unsigned long long* bufA = (const unsigned long long*)hbA;
  const unsigned long long* bufB = (const unsigned long long*)hbB;
  const size_t abase = (size_t)(bt * 16 + lr) * 128 + kh * 64 + lh * 2;

  for (int t = 0; t < SEQ; ++t) {
    const unsigned long long* cu = (t & 1) ? bufB : bufA;
    __hip_bfloat16* nxt = (t & 1) ? hbA : hbB;

    // ---- h fragments: direct global->reg, coherent relaxed loads ----
    bf16x8 afrag[8];
#pragma unroll
    for (int ks = 0; ks < 8; ++ks) {
      unsigned long long lo = __hip_atomic_load(&cu[abase + ks * 8],
          __ATOMIC_RELAXED, __HIP_MEMORY_SCOPE_AGENT);
      unsigned long long hi = __hip_atomic_load(&cu[abase + ks * 8 + 1],
          __ATOMIC_RELAXED, __HIP_MEMORY_SCOPE_AGENT);
      union { unsigned long long q[2]; bf16x8 v; } u;
      u.q[0] = lo; u.q[1] = hi;
      afrag[ks] = u.v;
    }

    // ---- MFMA: pure register operands ----
    f32x4 acc[3] = {};
#pragma unroll
    for (int ks = 0; ks < 8; ++ks)
#pragma unroll
      for (int f = 0; f < 3; ++f)
        acc[f] = __builtin_amdgcn_mfma_f32_16x16x32_bf16(afrag[ks], wfrag[ks][f], acc[f], 0, 0, 0);

#pragma unroll
    for (int f = 0; f < 3; ++f)
#pragma unroll
      for (int i = 0; i < 4; ++i)
        red[kh * 1600 + (lh * 4 + i) * 100 + ch * 48 + f * 16 + lr] = acc[f][i];
    __syncthreads();

    // ---- epilogue: 2 consecutive j per thread ----
    {
      float hn[2];
#pragma unroll
      for (int p = 0; p < 2; ++p) {
        int jl = jl0 + p;
        float rz = red[m * 100 + jl]      + red[1600 + m * 100 + jl];
        float rr = red[m * 100 + 32 + jl] + red[1600 + m * 100 + 32 + jl];
        float rh = red[m * 100 + 64 + jl] + red[1600 + m * 100 + 64 + jl];
        rz += brz[p]; rr += brr[p]; rh += brh[p];
        float z  = 1.f / (1.f + __expf(-(xzv[p] + rz)));
        float rg = 1.f / (1.f + __expf(-(xrv[p] + rr)));
        float hh = fmaxf(xhv[p] + rg * rh, 0.f);
        hn[p] = z * hreg[p] + (1.f - z) * hh;
        hreg[p] = hn[p];
      }
      if (t < SEQ - 1) {
        __hip_bfloat16 h0 = (__hip_bfloat16)hn[0], h1 = (__hip_bfloat16)hn[1];
        unsigned int pk = (unsigned int)*(unsigned short*)&h0 |
                          ((unsigned int)*(unsigned short*)&h1 << 16);
        __hip_atomic_store(
            (unsigned int*)&nxt[(size_t)b * HID + jg0], pk,
            __ATOMIC_RELAXED, __HIP_MEMORY_SCOPE_AGENT);

        // prefetch xp for t+1 (completes during the barrier wait)
        const __hip_bfloat16* xb_ = &xp[((size_t)b * SEQ + t + 1) * G3 + jg0];
        unsigned int uz = *(const unsigned int*)&xb_[0];
        unsigned int ur = *(const unsigned int*)&xb_[HID];
        unsigned int uh = *(const unsigned int*)&xb_[2 * HID];
        xzv[0] = (float)((__hip_bfloat16*)&uz)[0]; xzv[1] = (float)((__hip_bfloat16*)&uz)[1];
        xrv[0] = (float)((__hip_bfloat16*)&ur)[0]; xrv[1] = (float)((__hip_bfloat16*)&ur)[1];
        xhv[0] = (float)((__hip_bfloat16*)&uh)[0]; xhv[1] = (float)((__hip_bfloat16*)&uh)[1];
      }
    }

    // ---- group barrier: single-writer monotonic flags, relaxed only ----
    if (t < SEQ - 1) {
      __syncthreads();   // all waves' h stores vmcnt-drained before flag
      if (tid == 0) {
        __hip_atomic_store(&slots[bt * 32 + jt], t + 1,
                           __ATOMIC_RELAXED, __HIP_MEMORY_SCOPE_AGENT);
        for (;;) {
          int ok = 1;
#pragma unroll
          for (int i = 0; i < 16; ++i) {
            int v = __hip_atomic_load(&slots[bt * 32 + i],
                                      __ATOMIC_RELAXED, __HIP_MEMORY_SCOPE_AGENT);
            ok &= (v >= t + 1);
          }
          if (ok) break;
          __builtin_amdgcn_s_sleep(1);
        }
      }
      __syncthreads();
    }
  }

  // final fp32 h
#pragma unroll
  for (int p = 0; p < 2; ++p)
    h32[(size_t)b * HID + jg0 + p] = hreg[p];
}

// ---------------------------------------------------------------------------
// head: out[b] = h32[b][:] . Wd + bd
// ---------------------------------------------------------------------------
__global__ __launch_bounds__(64) void head_kernel(
    const float* __restrict__ h32, const float* __restrict__ Wd,
    const float* __restrict__ bd, float* __restrict__ out)
{
  int b = blockIdx.x, l = threadIdx.x;
  const float* hr = &h32[(size_t)b * HID];
  float s = 0.f;
#pragma unroll
  for (int i = 0; i < 8; ++i)
    s += hr[l + i * 64] * Wd[l + i * 64];
#pragma unroll
  for (int off = 32; off; off >>= 1) s += __shfl_down(s, off);
  if (l == 0) out[b] = s + bd[0];
}

// ---------------------------------------------------------------------------
extern "C" void kernel_launch(void* const* d_in, const int* in_sizes, int n_in,
                              void* d_out, int out_size, void* d_ws, size_t ws_size,
                              hipStream_t stream) {
  const float* x    = (const float*)d_in[0];
  const float* Wk   = (const float*)d_in[1];
  const float* Wr   = (const float*)d_in[2];
  const float* bias = (const float*)d_in[3];
  const float* Wd   = (const float*)d_in[4];
  const float* bd   = (const float*)d_in[5];
  float* out = (float*)d_out;

  char* ws = (char*)d_ws;
  size_t off = 0;
  __hip_bfloat16* xp  = (__hip_bfloat16*)(ws + off); off += (size_t)BATCH * SEQ * G3 * 2;
  __hip_bfloat16* xb  = (__hip_bfloat16*)(ws + off); off += (size_t)BATCH * SEQ * FEAT * 2;
  __hip_bfloat16* WkT = (__hip_bfloat16*)(ws + off); off += (size_t)G3 * FEAT * 2;
  __hip_bfloat16* WrT = (__hip_bfloat16*)(ws + off); off += (size_t)G3 * HID * 2;
  float*          h32 = (float*)(ws + off);          off += (size_t)BATCH * HID * 4;
  __hip_bfloat16* hb0 = (__hip_bfloat16*)(ws + off); off += (size_t)BATCH * HID * 2;
  __hip_bfloat16* hb1 = (__hip_bfloat16*)(ws + off); off += (size_t)BATCH * HID * 2;
  int*            slots = (int*)(ws + off);          off += 16 * 32 * sizeof(int);

  convert_bf16<<<(BATCH * SEQ * FEAT) / (256 * 8), 256, 0, stream>>>(x, xb, BATCH * SEQ * FEAT);
  transpose_convert<<<dim3(G3 / 32, FEAT / 32), 256, 0, stream>>>(Wk, WkT);
  transpose_convert<<<dim3(G3 / 32, HID  / 32), 256, 0, stream>>>(Wr, WrT);

  proj_mfma<<<dim3(G3 / 128, (BATCH * SEQ) / 128), 256, 0, stream>>>(xb, WkT, bias, xp);

  hipMemsetAsync(hb0, 0, (size_t)BATCH * HID * sizeof(__hip_bfloat16), stream);
  hipMemsetAsync(slots, 0, 16 * 32 * sizeof(int), stream);

  const float* br = bias + G3;
  {
    void* args[] = {(void*)&hb0, (void*)&hb1, (void*)&h32, (void*)&xp,
                    (void*)&WrT, (void*)&br, (void*)&slots};
    hipLaunchCooperativeKernel((void*)gru_persist, dim3(256), dim3(256),
                               args, 0, stream);
  }

  head_kernel<<<256, 64, 0, stream>>>(h32, Wd, bd, out);
}

// Round 7
// 453.920 us; speedup vs baseline: 2.1437x; 1.2156x over previous
//
#include <hip/hip_runtime.h>
#include <hip/hip_bf16.h>
#include <math.h>

constexpr int BATCH = 256;
constexpr int SEQ   = 128;
constexpr int FEAT  = 512;
constexpr int HID   = 512;
constexpr int G3    = 1536;

typedef __bf16 bf16x8 __attribute__((ext_vector_type(8)));
typedef float  f32x4  __attribute__((ext_vector_type(4)));
typedef int    i32x4v __attribute__((ext_vector_type(4)));

// ---------------------------------------------------------------------------
// fp32 -> bf16 convert (vectorized, 8/thread)
// ---------------------------------------------------------------------------
__global__ __launch_bounds__(256) void convert_bf16(
    const float* __restrict__ in, __hip_bfloat16* __restrict__ out, int n)
{
  int i = (blockIdx.x * 256 + threadIdx.x) * 8;
  if (i >= n) return;
  float4 v0 = *(const float4*)&in[i];
  float4 v1 = *(const float4*)&in[i + 4];
  __hip_bfloat16 o[8];
  o[0] = (__hip_bfloat16)v0.x; o[1] = (__hip_bfloat16)v0.y;
  o[2] = (__hip_bfloat16)v0.z; o[3] = (__hip_bfloat16)v0.w;
  o[4] = (__hip_bfloat16)v1.x; o[5] = (__hip_bfloat16)v1.y;
  o[6] = (__hip_bfloat16)v1.z; o[7] = (__hip_bfloat16)v1.w;
  *(int4*)&out[i] = *(int4*)o;
}

// ---------------------------------------------------------------------------
// transpose + convert: in[512][1536] f32 -> outT[1536][512] bf16
// ---------------------------------------------------------------------------
__global__ __launch_bounds__(256) void transpose_convert(
    const float* __restrict__ in, __hip_bfloat16* __restrict__ outT)
{
  __shared__ float tile[32][33];
  const int c0 = blockIdx.x * 32;
  const int r0 = blockIdx.y * 32;
  const int tid = threadIdx.x;
  {
    int row = tid >> 3, c4 = tid & 7;
    float4 v = *(const float4*)&in[(size_t)(r0 + row) * G3 + c0 + c4 * 4];
    tile[row][c4 * 4 + 0] = v.x;
    tile[row][c4 * 4 + 1] = v.y;
    tile[row][c4 * 4 + 2] = v.z;
    tile[row][c4 * 4 + 3] = v.w;
  }
  __syncthreads();
  {
    int rowT = tid >> 3, c4 = tid & 7;
    __hip_bfloat16 o[4];
#pragma unroll
    for (int e = 0; e < 4; ++e)
      o[e] = (__hip_bfloat16)tile[c4 * 4 + e][rowT];
    *(int2*)&outT[(size_t)(c0 + rowT) * FEAT + r0 + c4 * 4] = *(int2*)o;
  }
}

// ---------------------------------------------------------------------------
// proj: 128x128 tile, BK=64, 2-phase double-buffered global_load_lds with
// XOR source/read swizzle (0 bank conflicts, one barrier per K-tile).
// ---------------------------------------------------------------------------
__global__ __launch_bounds__(256) void proj_mfma(
    const __hip_bfloat16* __restrict__ xb, const __hip_bfloat16* __restrict__ WkT,
    const float* __restrict__ bias, __hip_bfloat16* __restrict__ xp)
{
  __shared__ __align__(16) __hip_bfloat16 As[2][128 * 64];
  __shared__ __align__(16) __hip_bfloat16 Bs[2][128 * 64];

  const int tid = threadIdx.x;
  const int wave = tid >> 6, l = tid & 63;
  const int wm = wave >> 1, wn = wave & 1;
  const int m0 = blockIdx.y * 128;
  const int n0 = blockIdx.x * 128;
  const int lr = l & 15, lh = l >> 4;
  const int swz = lr & 7;

  const int srow = l >> 3;
  const int schk = l & 7;
  const int wrow = wave * 32;

  f32x4 acc[4][4] = {};

#define PROJ_STAGE(K0, SEL)                                                      \
  {                                                                              \
    _Pragma("unroll")                                                            \
    for (int i = 0; i < 4; ++i) {                                                \
      int r = wrow + i * 8 + srow;                                               \
      const __hip_bfloat16* srcA =                                               \
          &xb[(size_t)(m0 + r) * FEAT + (K0) + ((schk ^ srow) * 8)];             \
      __builtin_amdgcn_global_load_lds(                                          \
          (const __attribute__((address_space(1))) void*)srcA,                   \
          (__attribute__((address_space(3))) void*)&As[SEL][(wrow + i * 8) * 64],\
          16, 0, 0);                                                             \
    }                                                                            \
    _Pragma("unroll")                                                            \
    for (int i = 0; i < 4; ++i) {                                                \
      int r = wrow + i * 8 + srow;                                               \
      const __hip_bfloat16* srcB =                                               \
          &WkT[(size_t)(n0 + r) * FEAT + (K0) + ((schk ^ srow) * 8)];            \
      __builtin_amdgcn_global_load_lds(                                          \
          (const __attribute__((address_space(1))) void*)srcB,                   \
          (__attribute__((address_space(3))) void*)&Bs[SEL][(wrow + i * 8) * 64],\
          16, 0, 0);                                                             \
    }                                                                            \
  }

  PROJ_STAGE(0, 0);
  __syncthreads();

  int cur = 0;
  for (int kt = 0; kt < 8; ++kt) {
    if (kt < 7) PROJ_STAGE((kt + 1) * 64, cur ^ 1);

#pragma unroll
    for (int ks = 0; ks < 2; ++ks) {
      bf16x8 a[4], b[4];
#pragma unroll
      for (int i = 0; i < 4; ++i) {
        int row = wm * 64 + i * 16 + lr;
        a[i] = *(const bf16x8*)&As[cur][row * 64 + (((ks * 4 + lh) ^ swz) * 8)];
      }
#pragma unroll
      for (int j = 0; j < 4; ++j) {
        int row = wn * 64 + j * 16 + lr;
        b[j] = *(const bf16x8*)&Bs[cur][row * 64 + (((ks * 4 + lh) ^ swz) * 8)];
      }
#pragma unroll
      for (int i = 0; i < 4; ++i)
#pragma unroll
        for (int j = 0; j < 4; ++j)
          acc[i][j] = __builtin_amdgcn_mfma_f32_16x16x32_bf16(a[i], b[j], acc[i][j], 0, 0, 0);
    }
    __syncthreads();
    cur ^= 1;
  }

  float bv[4];
#pragma unroll
  for (int j = 0; j < 4; ++j)
    bv[j] = bias[n0 + wn * 64 + j * 16 + lr];
#pragma unroll
  for (int i = 0; i < 4; ++i)
#pragma unroll
    for (int j = 0; j < 4; ++j) {
      int n = n0 + wn * 64 + j * 16 + lr;
#pragma unroll
      for (int r = 0; r < 4; ++r) {
        int m = m0 + wm * 64 + i * 16 + lh * 4 + r;
        xp[(size_t)m * G3 + n] = (__hip_bfloat16)(acc[i][j][r] + bv[j]);
      }
    }
#undef PROJ_STAGE
}

// ---------------------------------------------------------------------------
// Persistent GRU recurrence, v4: batched coherent loads.
//   - W register-stationary, PINNED via keep-alive asm (96 VGPR/lane).
//   - h fragments: ONE asm block of 8x global_load_dwordx4 sc0 sc1 + single
//     s_waitcnt (no per-load serialization).
//   - Flag poll: ONE asm block of 4x dwordx4 + single waitcnt per round.
// Grid 256: blockIdx.x = jt*16 + bt. LDS = 12.8 KB reduction buffer only.
// ---------------------------------------------------------------------------
__global__ __launch_bounds__(256, 1) void gru_persist(
    __hip_bfloat16* __restrict__ hbA, __hip_bfloat16* __restrict__ hbB,
    float* __restrict__ h32,
    const __hip_bfloat16* __restrict__ xp,
    const __hip_bfloat16* __restrict__ WrT,
    const float* __restrict__ br,
    int* slots)                               // [16][32] ints
{
  __shared__ float red[2 * 16 * 100];

  const int tid = threadIdx.x;
  const int bt = blockIdx.x & 15;
  const int jt = blockIdx.x >> 4;
  const int wave = tid >> 6, l = tid & 63;
  const int kh = wave & 1, ch = wave >> 1;
  const int lr = l & 15, lh = l >> 4;

  // ---- one-time: W fragments -> registers (24 x 16B per lane), pinned ----
  bf16x8 wfrag[8][3];
#pragma unroll
  for (int f = 0; f < 3; ++f) {
    int r = ch * 48 + f * 16 + lr;
    int n = (r >> 5) * HID + jt * 32 + (r & 31);
    const __hip_bfloat16* wp = &WrT[(size_t)n * HID + kh * 256 + lh * 8];
#pragma unroll
    for (int ks = 0; ks < 8; ++ks)
      wfrag[ks][f] = *(const bf16x8*)&wp[ks * 32];
  }
  // keep-alive: make this asm the definition point so the loads cannot be
  // rematerialized (re-issued) inside the t-loop.
  asm volatile(""
      : "+v"(wfrag[0][0]), "+v"(wfrag[0][1]), "+v"(wfrag[0][2]),
        "+v"(wfrag[1][0]), "+v"(wfrag[1][1]), "+v"(wfrag[1][2]),
        "+v"(wfrag[2][0]), "+v"(wfrag[2][1]), "+v"(wfrag[2][2]),
        "+v"(wfrag[3][0]), "+v"(wfrag[3][1]), "+v"(wfrag[3][2]),
        "+v"(wfrag[4][0]), "+v"(wfrag[4][1]), "+v"(wfrag[4][2]),
        "+v"(wfrag[5][0]), "+v"(wfrag[5][1]), "+v"(wfrag[5][2]),
        "+v"(wfrag[6][0]), "+v"(wfrag[6][1]), "+v"(wfrag[6][2]),
        "+v"(wfrag[7][0]), "+v"(wfrag[7][1]), "+v"(wfrag[7][2]));

  // ---- per-thread epilogue ownership ----
  const int m = tid >> 4, q4 = tid & 15;
  const int b = bt * 16 + m;
  const int jl0 = q4 * 2;
  const int jg0 = jt * 32 + jl0;
  float brz[2], brr[2], brh[2], hreg[2];
#pragma unroll
  for (int p = 0; p < 2; ++p) {
    brz[p] = br[jg0 + p];
    brr[p] = br[HID + jg0 + p];
    brh[p] = br[2 * HID + jg0 + p];
    hreg[p] = 0.f;
  }

  float xzv[2], xrv[2], xhv[2];
  {
    const __hip_bfloat16* xb_ = &xp[((size_t)b * SEQ + 0) * G3 + jg0];
    unsigned int uz = *(const unsigned int*)&xb_[0];
    unsigned int ur = *(const unsigned int*)&xb_[HID];
    unsigned int uh = *(const unsigned int*)&xb_[2 * HID];
    xzv[0] = (float)((__hip_bfloat16*)&uz)[0]; xzv[1] = (float)((__hip_bfloat16*)&uz)[1];
    xrv[0] = (float)((__hip_bfloat16*)&ur)[0]; xrv[1] = (float)((__hip_bfloat16*)&ur)[1];
    xhv[0] = (float)((__hip_bfloat16*)&uh)[0]; xhv[1] = (float)((__hip_bfloat16*)&uh)[1];
  }

  // per-lane h-fragment base (bytes): row (bt*16+lr), K-offset kh*256+lh*8 bf16
  const char* baseA = (const char*)hbA + ((size_t)(bt * 16 + lr) * HID + kh * 256 + lh * 8) * 2;
  const char* baseB = (const char*)hbB + ((size_t)(bt * 16 + lr) * HID + kh * 256 + lh * 8) * 2;

  for (int t = 0; t < SEQ; ++t) {
    const char* hp = (t & 1) ? baseB : baseA;
    __hip_bfloat16* nxt = (t & 1) ? hbA : hbB;

    // ---- h fragments: 8 batched coherent 16B loads, ONE waitcnt ----
    i32x4v r0, r1, r2, r3, r4, r5, r6, r7;
    asm volatile(
        "global_load_dwordx4 %0, %8, off sc0 sc1\n\t"
        "global_load_dwordx4 %1, %8, off offset:64 sc0 sc1\n\t"
        "global_load_dwordx4 %2, %8, off offset:128 sc0 sc1\n\t"
        "global_load_dwordx4 %3, %8, off offset:192 sc0 sc1\n\t"
        "global_load_dwordx4 %4, %8, off offset:256 sc0 sc1\n\t"
        "global_load_dwordx4 %5, %8, off offset:320 sc0 sc1\n\t"
        "global_load_dwordx4 %6, %8, off offset:384 sc0 sc1\n\t"
        "global_load_dwordx4 %7, %8, off offset:448 sc0 sc1\n\t"
        "s_waitcnt vmcnt(0)"
        : "=&v"(r0), "=&v"(r1), "=&v"(r2), "=&v"(r3),
          "=&v"(r4), "=&v"(r5), "=&v"(r6), "=&v"(r7)
        : "v"(hp)
        : "memory");
    union { i32x4v q; bf16x8 v; } u0, u1, u2, u3, u4, u5, u6, u7;
    u0.q = r0; u1.q = r1; u2.q = r2; u3.q = r3;
    u4.q = r4; u5.q = r5; u6.q = r6; u7.q = r7;
    bf16x8 afrag[8] = {u0.v, u1.v, u2.v, u3.v, u4.v, u5.v, u6.v, u7.v};

    // ---- MFMA: pure register operands ----
    f32x4 acc[3] = {};
#pragma unroll
    for (int ks = 0; ks < 8; ++ks)
#pragma unroll
      for (int f = 0; f < 3; ++f)
        acc[f] = __builtin_amdgcn_mfma_f32_16x16x32_bf16(afrag[ks], wfrag[ks][f], acc[f], 0, 0, 0);

#pragma unroll
    for (int f = 0; f < 3; ++f)
#pragma unroll
      for (int i = 0; i < 4; ++i)
        red[kh * 1600 + (lh * 4 + i) * 100 + ch * 48 + f * 16 + lr] = acc[f][i];
    __syncthreads();

    // ---- epilogue ----
    {
      float hn[2];
#pragma unroll
      for (int p = 0; p < 2; ++p) {
        int jl = jl0 + p;
        float rz = red[m * 100 + jl]      + red[1600 + m * 100 + jl];
        float rr = red[m * 100 + 32 + jl] + red[1600 + m * 100 + 32 + jl];
        float rh = red[m * 100 + 64 + jl] + red[1600 + m * 100 + 64 + jl];
        rz += brz[p]; rr += brr[p]; rh += brh[p];
        float z  = 1.f / (1.f + __expf(-(xzv[p] + rz)));
        float rg = 1.f / (1.f + __expf(-(xrv[p] + rr)));
        float hh = fmaxf(xhv[p] + rg * rh, 0.f);
        hn[p] = z * hreg[p] + (1.f - z) * hh;
        hreg[p] = hn[p];
      }
      if (t < SEQ - 1) {
        __hip_bfloat16 h0 = (__hip_bfloat16)hn[0], h1 = (__hip_bfloat16)hn[1];
        unsigned int pk = (unsigned int)*(unsigned short*)&h0 |
                          ((unsigned int)*(unsigned short*)&h1 << 16);
        __hip_atomic_store(
            (unsigned int*)&nxt[(size_t)b * HID + jg0], pk,
            __ATOMIC_RELAXED, __HIP_MEMORY_SCOPE_AGENT);

        const __hip_bfloat16* xb_ = &xp[((size_t)b * SEQ + t + 1) * G3 + jg0];
        unsigned int uz = *(const unsigned int*)&xb_[0];
        unsigned int ur = *(const unsigned int*)&xb_[HID];
        unsigned int uh = *(const unsigned int*)&xb_[2 * HID];
        xzv[0] = (float)((__hip_bfloat16*)&uz)[0]; xzv[1] = (float)((__hip_bfloat16*)&uz)[1];
        xrv[0] = (float)((__hip_bfloat16*)&ur)[0]; xrv[1] = (float)((__hip_bfloat16*)&ur)[1];
        xhv[0] = (float)((__hip_bfloat16*)&uh)[0]; xhv[1] = (float)((__hip_bfloat16*)&uh)[1];
      }
    }

    // ---- group barrier: single-writer flags, batched poll ----
    if (t < SEQ - 1) {
      __syncthreads();   // drains all waves' vmcnt -> h stores visible
      if (tid == 0) {
        __hip_atomic_store(&slots[bt * 32 + jt], t + 1,
                           __ATOMIC_RELAXED, __HIP_MEMORY_SCOPE_AGENT);
        const char* fl = (const char*)&slots[bt * 32];
        for (;;) {
          i32x4v p0, p1, p2, p3;
          asm volatile(
              "global_load_dwordx4 %0, %4, off sc0 sc1\n\t"
              "global_load_dwordx4 %1, %4, off offset:16 sc0 sc1\n\t"
              "global_load_dwordx4 %2, %4, off offset:32 sc0 sc1\n\t"
              "global_load_dwordx4 %3, %4, off offset:48 sc0 sc1\n\t"
              "s_waitcnt vmcnt(0)"
              : "=&v"(p0), "=&v"(p1), "=&v"(p2), "=&v"(p3)
              : "v"(fl)
              : "memory");
          int t1 = t + 1;
          int ok = (p0[0] >= t1) & (p0[1] >= t1) & (p0[2] >= t1) & (p0[3] >= t1) &
                   (p1[0] >= t1) & (p1[1] >= t1) & (p1[2] >= t1) & (p1[3] >= t1) &
                   (p2[0] >= t1) & (p2[1] >= t1) & (p2[2] >= t1) & (p2[3] >= t1) &
                   (p3[0] >= t1) & (p3[1] >= t1) & (p3[2] >= t1) & (p3[3] >= t1);
          if (ok) break;
          __builtin_amdgcn_s_sleep(1);
        }
      }
      __syncthreads();
    }
  }

  // final fp32 h
#pragma unroll
  for (int p = 0; p < 2; ++p)
    h32[(size_t)b * HID + jg0 + p] = hreg[p];
}

// ---------------------------------------------------------------------------
// head: out[b] = h32[b][:] . Wd + bd
// ---------------------------------------------------------------------------
__global__ __launch_bounds__(64) void head_kernel(
    const float* __restrict__ h32, const float* __restrict__ Wd,
    const float* __restrict__ bd, float* __restrict__ out)
{
  int b = blockIdx.x, l = threadIdx.x;
  const float* hr = &h32[(size_t)b * HID];
  float s = 0.f;
#pragma unroll
  for (int i = 0; i < 8; ++i)
    s += hr[l + i * 64] * Wd[l + i * 64];
#pragma unroll
  for (int off = 32; off; off >>= 1) s += __shfl_down(s, off);
  if (l == 0) out[b] = s + bd[0];
}

// ---------------------------------------------------------------------------
extern "C" void kernel_launch(void* const* d_in, const int* in_sizes, int n_in,
                              void* d_out, int out_size, void* d_ws, size_t ws_size,
                              hipStream_t stream) {
  const float* x    = (const float*)d_in[0];
  const float* Wk   = (const float*)d_in[1];
  const float* Wr   = (const float*)d_in[2];
  const float* bias = (const float*)d_in[3];
  const float* Wd   = (const float*)d_in[4];
  const float* bd   = (const float*)d_in[5];
  float* out = (float*)d_out;

  char* ws = (char*)d_ws;
  size_t off = 0;
  __hip_bfloat16* xp  = (__hip_bfloat16*)(ws + off); off += (size_t)BATCH * SEQ * G3 * 2;
  __hip_bfloat16* xb  = (__hip_bfloat16*)(ws + off); off += (size_t)BATCH * SEQ * FEAT * 2;
  __hip_bfloat16* WkT = (__hip_bfloat16*)(ws + off); off += (size_t)G3 * FEAT * 2;
  __hip_bfloat16* WrT = (__hip_bfloat16*)(ws + off); off += (size_t)G3 * HID * 2;
  float*          h32 = (float*)(ws + off);          off += (size_t)BATCH * HID * 4;
  __hip_bfloat16* hb0 = (__hip_bfloat16*)(ws + off); off += (size_t)BATCH * HID * 2;
  __hip_bfloat16* hb1 = (__hip_bfloat16*)(ws + off); off += (size_t)BATCH * HID * 2;
  int*            slots = (int*)(ws + off);          off += 16 * 32 * sizeof(int);

  convert_bf16<<<(BATCH * SEQ * FEAT) / (256 * 8), 256, 0, stream>>>(x, xb, BATCH * SEQ * FEAT);
  transpose_convert<<<dim3(G3 / 32, FEAT / 32), 256, 0, stream>>>(Wk, WkT);
  transpose_convert<<<dim3(G3 / 32, HID  / 32), 256, 0, stream>>>(Wr, WrT);

  proj_mfma<<<dim3(G3 / 128, (BATCH * SEQ) / 128), 256, 0, stream>>>(xb, WkT, bias, xp);

  hipMemsetAsync(hb0, 0, (size_t)BATCH * HID * sizeof(__hip_bfloat16), stream);
  hipMemsetAsync(slots, 0, 16 * 32 * sizeof(int), stream);

  const float* br = bias + G3;
  {
    void* args[] = {(void*)&hb0, (void*)&hb1, (void*)&h32, (void*)&xp,
                    (void*)&WrT, (void*)&br, (void*)&slots};
    hipLaunchCooperativeKernel((void*)gru_persist, dim3(256), dim3(256),
                               args, 0, stream);
  }

  head_kernel<<<256, 64, 0, stream>>>(h32, Wd, bd, out);
}